// Round 12
// baseline (412.167 us; speedup 1.0000x reference)
//
#include <hip/hip_runtime.h>
#include <hip/hip_bf16.h>

// GCN: h1 = relu(Agg(x@W1)+b1); h2 = relu(Agg(h1@W2)+b2); out = mean(h2)@Wc + bc
// Agg via CSR gather; g = (X@W)*dinv stored OCP fp8 e4m3 (128B node-major rows,
// plus ONE ZERO ROW at index N for CSR padding).
// r12: agg REVERTED to r10 pair form (r11 quad regressed: VGPR 50->80 cut
// occupancy 8->6 waves/SIMD + slot inflation; pair = latency/occupancy sweet
// spot, agg at its ~88MB compulsory-FETCH floor). BUILD CHAIN REWRITTEN:
// old hist2/rowsum/rowoff/fill2/bucket_scat two-pass (binned 6.4MB write+read,
// ECAP LDS staging) -> direct: histN (global-atomic degree hist, 1.6M adds
// spread over 6250 L2 lines, ~256/line) + pairsum/bscan/cursorpad (per-bucket
// LDS scans -> EXACT r10 pair-padded layout, exact-sized regions) + scatter
// (single E-pass, q=atomicAdd(qcur[dst]), direct slot write). Slot math
// bit-identical to r10 bucket_scat.
// r10: PAIR agg: wave = 2 nodes (lanes 0-31 A, 32-63 B, 4 feats/lane), gather
// = 256B = 2 edges/VMEM instr; pair-padded round-interleaved CSR (16A|16B).
// r9: padded CSR kills tail masking. [r8 inline-asm s_load aborted on HW]
// r7: masked tail. r6: pool atomic serialization fix (62->6us; lesson: global
// atomics on FEW lines serialize write-through). r5: 32-bit byte offsets.
// r4: fp8 activations. r1-r3: plane-sharded gather strictly worse.
// NOTE: harness re-poisons 256MB workspace per iteration (~40us fill) -
// untouchable; controllable budget ~= dur - 40us.
// GEMMs: mfma_f32_16x16x32_bf16, LDS-free, W pre-packed to k-block layout.

#define FEAT 128
#define PBLK 512        // pool stage-1 blocks

typedef __attribute__((ext_vector_type(8))) short short8;
typedef __attribute__((ext_vector_type(4))) float float4v;
typedef __attribute__((ext_vector_type(2))) float floatx2;

union I4S8 { int4 i; short8 s; };

static __device__ inline unsigned short f2bf(float f) {
    union { __hip_bfloat16 h; unsigned short u; } cv;
    cv.h = __float2bfloat16(f);
    return cv.u;
}

// ---- OCP fp8 e4m3 helpers ----
static __device__ inline floatx2 fp8x2_dec(unsigned int u) {
#if __has_builtin(__builtin_amdgcn_cvt_pk_f32_fp8)
    return __builtin_amdgcn_cvt_pk_f32_fp8((int)u, false);
#else
    floatx2 r;
    unsigned int b0 = u & 0xFFu, b1 = (u >> 8) & 0xFFu;
    r.x = __uint_as_float(((b0 & 0x80u) << 24) | ((b0 & 0x7Fu) << 20)) * 0x1p+120f;
    r.y = __uint_as_float(((b1 & 0x80u) << 24) | ((b1 & 0x7Fu) << 20)) * 0x1p+120f;
    return r;
#endif
}

static __device__ inline floatx2 fp8x2_dec_hi(unsigned int u) {
#if __has_builtin(__builtin_amdgcn_cvt_pk_f32_fp8)
    return __builtin_amdgcn_cvt_pk_f32_fp8((int)u, true);
#else
    return fp8x2_dec(u >> 16);
#endif
}

// pack two floats -> two fp8 e4m3 bytes (low word)
static __device__ inline unsigned short fp8x2_enc(float x, float y) {
#if __has_builtin(__builtin_amdgcn_cvt_pk_fp8_f32)
    return (unsigned short)(__builtin_amdgcn_cvt_pk_fp8_f32(x, y, 0, false) & 0xFFFF);
#else
    auto enc1 = [](float f) -> unsigned int {
        unsigned int u = __float_as_uint(f);
        unsigned int s = (u >> 24) & 0x80u;
        float a = fabsf(f);
        a = fminf(a, 448.0f);
        unsigned int code;
        if (a < 0.015625f) {
            code = (unsigned int)(int)rintf(a * 512.0f);
        } else {
            unsigned int au = __float_as_uint(a);
            unsigned int r = au + 0x0007FFFFu + ((au >> 20) & 1u);
            unsigned int e = (r >> 23) - 120u;
            unsigned int m = (r >> 20) & 7u;
            code = (e << 3) | m;
            if (code > 0x7Eu) code = 0x7Eu;
        }
        return code | s;
    };
    return (unsigned short)(enc1(x) | (enc1(y) << 8));
#endif
}

static __device__ inline unsigned char fp8enc(float f) {
#if __has_builtin(__builtin_amdgcn_cvt_pk_fp8_f32)
    return (unsigned char)(__builtin_amdgcn_cvt_pk_fp8_f32(f, 0.0f, 0, false) & 0xFF);
#else
    return (unsigned char)(fp8x2_enc(f, 0.0f) & 0xFF);
#endif
}

// ---- build 1: per-node degree histogram (global atomics, L2-resident) ----
__global__ __launch_bounds__(256) void histN(const int* __restrict__ dst,
                                             int* __restrict__ cnt, int nE) {
    int stride = gridDim.x * 256;
    for (int e = blockIdx.x * 256 + threadIdx.x; e < nE; e += stride)
        atomicAdd(&cnt[dst[e]], 1);
}

// ---- build 2: per-bucket pair-slot totals (LDS scan over 128 pairs) ----
// pairSlots(p) = 2 * ceil(max(degA,degB)/16) * 16  (0 if both empty)
__global__ __launch_bounds__(256) void pairsum_k(const int* __restrict__ cnt,
                                                 int* __restrict__ btot, int n) {
    __shared__ int lcnt[256];
    __shared__ int ssc[256];
    int b = blockIdx.x, t = threadIdx.x;
    int node0 = b << 8;
    int nloc = min(256, n - node0);
    lcnt[t] = (t < nloc) ? cnt[node0 + t] : 0;
    __syncthreads();
    int pairSlots = 0;
    if (t < 128) {
        int mx = max(lcnt[2 * t], lcnt[2 * t + 1]);
        pairSlots = ((mx + 15) & ~15) << 1;
    }
    ssc[t] = pairSlots;
    __syncthreads();
    for (int o = 1; o < 256; o <<= 1) {
        int add = (t >= o) ? ssc[t - o] : 0;
        __syncthreads();
        ssc[t] += add;
        __syncthreads();
    }
    if (t == 255) btot[b] = ssc[255];
}

// ---- build 3: exclusive scan of bucket slot totals (nbuck <= 512) ----
__global__ __launch_bounds__(512) void bscan_k(const int* __restrict__ btot,
                                               int* __restrict__ bboff, int nbuck) {
    __shared__ int sc[512];
    int t = threadIdx.x;
    int v = (t < nbuck) ? btot[t] : 0;
    sc[t] = v;
    __syncthreads();
    for (int o = 1; o < 512; o <<= 1) {
        int add = (t >= o) ? sc[t - o] : 0;
        __syncthreads();
        sc[t] += add;
        __syncthreads();
    }
    if (t < nbuck) {
        bboff[t] = sc[t] - v;
        if (t == nbuck - 1) bboff[nbuck] = sc[t];
    }
}

// ---- build 4: cursor/cnt/dinv + zero-pad fill (r10-identical layout) ----
// Pair region at bboff[b]+poff[p] (slot units; multiples of 32 -> aligned).
// Node (p,h) slot q -> base + (q>>4)*32 + h*16 + (q&15). Pads (q in
// [deg,pairLen)) -> zOff. cnt[node] := pairLen, cursor[node] := pair base.
__global__ __launch_bounds__(256) void cursorpad_k(int* __restrict__ cnt,
                                                   const int* __restrict__ bboff,
                                                   int* __restrict__ cursor,
                                                   float* __restrict__ dinv,
                                                   int* __restrict__ qcur,
                                                   int* __restrict__ csr_src, int n) {
    __shared__ int lcnt[256];
    __shared__ int ssc[256];
    __shared__ int poff[128];
    int b = blockIdx.x, t = threadIdx.x;
    int node0 = b << 8;
    int nloc = min(256, n - node0);
    int pbase = bboff[b];
    int zOff = n << 7;                          // zero-row byte offset
    lcnt[t] = (t < nloc) ? cnt[node0 + t] : 0;
    __syncthreads();
    int pairSlots = 0;
    if (t < 128) {
        int mx = max(lcnt[2 * t], lcnt[2 * t + 1]);
        pairSlots = ((mx + 15) & ~15) << 1;
    }
    ssc[t] = pairSlots;
    __syncthreads();
    for (int o = 1; o < 256; o <<= 1) {
        int add = (t >= o) ? ssc[t - o] : 0;
        __syncthreads();
        ssc[t] += add;
        __syncthreads();
    }
    if (t < 128) poff[t] = ssc[t] - pairSlots;  // exclusive pair offset
    __syncthreads();
    int p = t >> 1, h = t & 1;
    int pl = ((max(lcnt[p * 2], lcnt[p * 2 + 1]) + 15) & ~15);
    if (t < nloc) {
        int deg = lcnt[t];
        cnt[node0 + t] = pl;                    // pairLen (agg loop bound)
        dinv[node0 + t] = rsqrtf((float)(deg + 1));
        cursor[node0 + t] = pbase + poff[p];    // pair base (slot units)
        qcur[node0 + t] = 0;                    // scatter cursor reset
    }
    // pad fill: both halves of every non-empty pair (incl. ghost partner)
    int nlocp = (nloc + 1) & ~1;
    if (t < nlocp) {
        int deg = (t < nloc) ? lcnt[t] : 0;
        int base = pbase + poff[p] + (h << 4);
        for (int q = deg; q < pl; q++)
            csr_src[base + ((q >> 4) << 5) + (q & 15)] = zOff;
    }
}

// ---- build 5: direct scatter into pair-padded CSR (global cursor) ----
__global__ __launch_bounds__(256) void scatter_k(const int* __restrict__ src,
                                                 const int* __restrict__ dst,
                                                 const int* __restrict__ cursor,
                                                 int* __restrict__ qcur,
                                                 int* __restrict__ csr_src, int nE) {
    int stride = gridDim.x * 256;
    for (int e = blockIdx.x * 256 + threadIdx.x; e < nE; e += stride) {
        int d = dst[e];
        int s = src[e];
        int q = atomicAdd(&qcur[d], 1);
        int slot = cursor[d] + ((q >> 4) << 5) + ((d & 1) << 4) + (q & 15);
        csr_src[slot] = s << 7;                 // pre-shifted row byte offset
    }
}

// ---- W pre-pack (both layers) + gbuf zero row + cnt zero ----
__global__ __launch_bounds__(256) void wprep2(const float* __restrict__ W1,
                                              const float* __restrict__ W2,
                                              unsigned short* __restrict__ Wbf1,
                                              unsigned short* __restrict__ Wbf2,
                                              unsigned char* __restrict__ gbuf,
                                              int* __restrict__ cnt,
                                              int n) {
    int tid = blockIdx.x * 256 + threadIdx.x;   // 32768 threads
    if (tid < 32)
        ((unsigned int*)(gbuf + (size_t)n * FEAT))[tid] = 0u;  // zero row N
    for (int i = tid; i < n; i += 32768) cnt[i] = 0;
    const float* W = (tid < 16384) ? W1 : W2;
    unsigned short* O = (tid < 16384) ? Wbf1 : Wbf2;
    int id = tid & 16383;
    int chunk = id >> 3, j = id & 7;
    int kb = chunk >> 7, nn = chunk & 127;
    O[id] = f2bf(W[(kb * 8 + j) * FEAT + nn]);
}

// ---- MFMA GEMM: gout[N][128](fp8) = bf16(X) @ Wbf * dinv[row] ----
// AFP32=true: X is fp32 rows. AFP32=false: X is fp8 e4m3 rows (exact->bf16).
template <bool AFP32>
__global__ __launch_bounds__(256) void gemm_mfma(const void* __restrict__ Xv,
                                                 const unsigned short* __restrict__ Wbf,
                                                 const float* __restrict__ dinv,
                                                 unsigned char* __restrict__ gout,
                                                 int n) {
    int wave = threadIdx.x >> 6, lane = threadIdx.x & 63;
    int m0 = blockIdx.x * 64 + wave * 16;
    if (m0 >= n) return;
    int col = lane & 15, quad = lane >> 4;
    int mc = min(m0 + col, n - 1);

    short8 afr[4];
    if (AFP32) {
        const float* X = (const float*)Xv;
        const float* xr = X + (size_t)mc * FEAT + quad * 8;
#pragma unroll
        for (int ks = 0; ks < 4; ks++) {
            float4 lo = *(const float4*)(xr + ks * 32);
            float4 hi = *(const float4*)(xr + ks * 32 + 4);
            short8 a;
            a[0] = (short)f2bf(lo.x); a[1] = (short)f2bf(lo.y);
            a[2] = (short)f2bf(lo.z); a[3] = (short)f2bf(lo.w);
            a[4] = (short)f2bf(hi.x); a[5] = (short)f2bf(hi.y);
            a[6] = (short)f2bf(hi.z); a[7] = (short)f2bf(hi.w);
            afr[ks] = a;
        }
    } else {
        const unsigned char* X8 = (const unsigned char*)Xv;
        const unsigned char* xr = X8 + (size_t)mc * FEAT + quad * 8;
#pragma unroll
        for (int ks = 0; ks < 4; ks++) {
            uint2 u2 = *(const uint2*)(xr + ks * 32);
            floatx2 p0 = fp8x2_dec(u2.x);
            floatx2 p1 = fp8x2_dec_hi(u2.x);
            floatx2 p2 = fp8x2_dec(u2.y);
            floatx2 p3 = fp8x2_dec_hi(u2.y);
            short8 a;
            a[0] = (short)f2bf(p0.x); a[1] = (short)f2bf(p0.y);
            a[2] = (short)f2bf(p1.x); a[3] = (short)f2bf(p1.y);
            a[4] = (short)f2bf(p2.x); a[5] = (short)f2bf(p2.y);
            a[6] = (short)f2bf(p3.x); a[7] = (short)f2bf(p3.y);
            afr[ks] = a;
        }
    }

    float dvr[4];
#pragma unroll
    for (int r = 0; r < 4; r++)
        dvr[r] = dinv[min(m0 + quad * 4 + r, n - 1)];

    const int4* Wb = (const int4*)Wbf;
#pragma unroll
    for (int nt = 0; nt < 8; nt++) {
        float4v acc = {0.f, 0.f, 0.f, 0.f};
#pragma unroll
        for (int ks = 0; ks < 4; ks++) {
            int kb = ks * 4 + quad;
            I4S8 u; u.i = Wb[kb * FEAT + nt * 16 + col];
            acc = __builtin_amdgcn_mfma_f32_16x16x32_bf16(afr[ks], u.s, acc, 0, 0, 0);
        }
#pragma unroll
        for (int r = 0; r < 4; r++) {
            int row = m0 + quad * 4 + r;
            if (row < n)
                gout[(size_t)row * FEAT + nt * 16 + col] = fp8enc(acc[r] * dvr[r]);
        }
    }
}

// ---- agg: PAIRED CSR gather + bias + relu -> fp8 rows (2 nodes per wave) ----
// lanes 0-31 = node A, 32-63 = node B; each lane owns 4 feats (1 dword).
// Gather instr = dword x64 = 2 rows = 2 edges. Idx: each half loads its own
// 16-idx block (4 int4 at pairBase + r*128 + half*64). Rounds = pairLen/16.
__global__ __launch_bounds__(256) void agg_csr(const int* __restrict__ cursor,
                                               const int* __restrict__ cnt,
                                               const int* __restrict__ csr_src,
                                               const unsigned char* __restrict__ gbuf,
                                               const float* __restrict__ dinv,
                                               const float* __restrict__ bias,
                                               unsigned char* __restrict__ outb,
                                               int n) {
    int pair = blockIdx.x * 4 + (threadIdx.x >> 6);
    int nodeA = pair << 1;
    if (nodeA >= n) return;
    unsigned lane = threadIdx.x & 63;
    unsigned half = lane >> 5;                  // 0 = A, 1 = B
    unsigned sub = lane & 31;
    int node = nodeA + (int)half;               // n even -> node < n
    unsigned fb = sub << 2;                     // 4B feature offset in row

    int curS = __builtin_amdgcn_readfirstlane(cursor[nodeA]);  // pair base (slots)
    int plS = __builtin_amdgcn_readfirstlane(cnt[nodeA]);      // pairLen
    const unsigned char* csrB = (const unsigned char*)csr_src;
    const unsigned char* ip0 = csrB + (((size_t)(unsigned)curS) << 2) + (half << 6);

    unsigned su = *(const unsigned*)(gbuf + ((((unsigned)node) << 7) | fb));
    floatx2 a01 = fp8x2_dec(su), a23 = fp8x2_dec_hi(su);       // self-loop
    floatx2 b01 = {0.f, 0.f}, b23 = {0.f, 0.f};

    int rounds = plS >> 4;
    for (int r = 0; r < rounds; r++) {
        const unsigned char* p = ip0 + ((size_t)(unsigned)r << 7);
        int4 w0 = *(const int4*)(p);
        int4 w1 = *(const int4*)(p + 16);
        int4 w2 = *(const int4*)(p + 32);
        int4 w3 = *(const int4*)(p + 48);
        unsigned uu[16];
        uu[0]  = *(const unsigned*)(gbuf + ((unsigned)w0.x | fb));
        uu[1]  = *(const unsigned*)(gbuf + ((unsigned)w0.y | fb));
        uu[2]  = *(const unsigned*)(gbuf + ((unsigned)w0.z | fb));
        uu[3]  = *(const unsigned*)(gbuf + ((unsigned)w0.w | fb));
        uu[4]  = *(const unsigned*)(gbuf + ((unsigned)w1.x | fb));
        uu[5]  = *(const unsigned*)(gbuf + ((unsigned)w1.y | fb));
        uu[6]  = *(const unsigned*)(gbuf + ((unsigned)w1.z | fb));
        uu[7]  = *(const unsigned*)(gbuf + ((unsigned)w1.w | fb));
        uu[8]  = *(const unsigned*)(gbuf + ((unsigned)w2.x | fb));
        uu[9]  = *(const unsigned*)(gbuf + ((unsigned)w2.y | fb));
        uu[10] = *(const unsigned*)(gbuf + ((unsigned)w2.z | fb));
        uu[11] = *(const unsigned*)(gbuf + ((unsigned)w2.w | fb));
        uu[12] = *(const unsigned*)(gbuf + ((unsigned)w3.x | fb));
        uu[13] = *(const unsigned*)(gbuf + ((unsigned)w3.y | fb));
        uu[14] = *(const unsigned*)(gbuf + ((unsigned)w3.z | fb));
        uu[15] = *(const unsigned*)(gbuf + ((unsigned)w3.w | fb));
#pragma unroll
        for (int k = 0; k < 16; k += 2) {
            a01 += fp8x2_dec(uu[k]);
            a23 += fp8x2_dec_hi(uu[k]);
            b01 += fp8x2_dec(uu[k + 1]);
            b23 += fp8x2_dec_hi(uu[k + 1]);
        }
    }
    a01 += b01;
    a23 += b23;
    float dv = dinv[node];
    float4 bv = ((const float4*)bias)[sub];
    float r0 = fmaxf(a01.x * dv + bv.x, 0.0f);
    float r1 = fmaxf(a01.y * dv + bv.y, 0.0f);
    float r2 = fmaxf(a23.x * dv + bv.z, 0.0f);
    float r3 = fmaxf(a23.y * dv + bv.w, 0.0f);
    unsigned outw = (unsigned)fp8x2_enc(r0, r1) | ((unsigned)fp8x2_enc(r2, r3) << 16);
    *(unsigned*)(outb + ((((unsigned)node) << 7) | fb)) = outw;
}

// ---- mean pool stage 1: per-block partial sums, NO global atomics ----
__global__ __launch_bounds__(256) void pool_kernel(const unsigned char* __restrict__ a,
                                                   float* __restrict__ partial, int n) {
    __shared__ float red[16][132];   // +4 pad
    int t = threadIdx.x, b = blockIdx.x;
    int fg = t & 15;
    int rg = t >> 4;
    unsigned fb = (unsigned)fg << 3;             // feature byte offset
    floatx2 s01 = {0.f, 0.f}, s23 = {0.f, 0.f}, s45 = {0.f, 0.f}, s67 = {0.f, 0.f};
    for (int i = (b << 4) | rg; i < n; i += PBLK * 16) {
        uint2 u2 = *(const uint2*)(a + (((unsigned)i << 7) | fb));
        s01 += fp8x2_dec(u2.x);
        s23 += fp8x2_dec_hi(u2.x);
        s45 += fp8x2_dec(u2.y);
        s67 += fp8x2_dec_hi(u2.y);
    }
    red[rg][fb + 0] = s01.x; red[rg][fb + 1] = s01.y;
    red[rg][fb + 2] = s23.x; red[rg][fb + 3] = s23.y;
    red[rg][fb + 4] = s45.x; red[rg][fb + 5] = s45.y;
    red[rg][fb + 6] = s67.x; red[rg][fb + 7] = s67.y;
    __syncthreads();
    if (t < FEAT) {
        float s = 0.0f;
#pragma unroll
        for (int k = 0; k < 16; k++) s += red[k][t];
        partial[b * FEAT + t] = s;
    }
}

// ---- final: reduce partials; out[c] = (pooled/N) . Wc[:,c] + bc[c] ----
__global__ __launch_bounds__(128) void final_kernel(const float* __restrict__ partial,
                                                    const float* __restrict__ Wc,
                                                    const float* __restrict__ bc,
                                                    float* __restrict__ out,
                                                    int n, int C) {
    __shared__ float p[FEAT];
    int t = threadIdx.x;
    float s = 0.0f;
    for (int b = 0; b < PBLK; b++) s += partial[b * FEAT + t];
    p[t] = s * (1.0f / (float)n);
    __syncthreads();
    if (t < C) {
        float acc = bc[t];
        for (int h = 0; h < FEAT; h++)
            acc += p[h] * Wc[h * C + t];
        out[t] = acc;
    }
}

extern "C" void kernel_launch(void* const* d_in, const int* in_sizes, int n_in,
                              void* d_out, int out_size, void* d_ws, size_t ws_size,
                              hipStream_t stream) {
    const float* x  = (const float*)d_in[0];
    const int*   ei = (const int*)d_in[1];
    const float* W1 = (const float*)d_in[2];
    const float* b1 = (const float*)d_in[3];
    const float* W2 = (const float*)d_in[4];
    const float* b2 = (const float*)d_in[5];
    const float* Wc = (const float*)d_in[6];
    const float* bc = (const float*)d_in[7];

    const int N = in_sizes[0] / FEAT;        // 100000
    const int E = in_sizes[1] / 2;           // 1600000
    const int C = out_size;                  // 32
    const int* srcI = ei;
    const int* dstI = ei + E;
    const int NBK = (N + 255) >> 8;          // node buckets (391)
    // pair-padded slots <= 2*ne_b + 128*30 per bucket -> 2E + NBK*3840 total
    const size_t csrCap = (size_t)2 * E + (size_t)NBK * 3840 + 64;

    // workspace carve (256B aligned)
    auto align256 = [](size_t v) { return (v + 255) & ~(size_t)255; };
    char* w = (char*)d_ws;
    int*            cnt     = (int*)w;            w += align256((size_t)N * 4);
    float*          dinv    = (float*)w;          w += align256((size_t)N * 4);
    int*            cursor  = (int*)w;            w += align256((size_t)N * 4);
    int*            qcur    = (int*)w;            w += align256((size_t)N * 4);
    int*            csr_src = (int*)w;            w += align256(csrCap * 4);
    int*            btot    = (int*)w;            w += align256((size_t)NBK * 4);
    int*            bboff   = (int*)w;            w += align256((size_t)(NBK + 1) * 4);
    unsigned short* Wbf1    = (unsigned short*)w; w += align256((size_t)FEAT * FEAT * 2);
    unsigned short* Wbf2    = (unsigned short*)w; w += align256((size_t)FEAT * FEAT * 2);
    unsigned char*  gbuf    = (unsigned char*)w;  w += align256((size_t)(N + 1) * FEAT);
    unsigned char*  bufA    = (unsigned char*)w;  w += align256((size_t)N * FEAT);
    float*          partial = (float*)w;          w += align256((size_t)PBLK * FEAT * 4);

    // W pre-pack + gbuf zero row + cnt zero
    wprep2<<<128, 256, 0, stream>>>(W1, W2, Wbf1, Wbf2, gbuf, cnt, N);

    // ---- direct CSR build: degree hist -> pair scan -> cursor/pad -> scatter
    histN<<<1563, 256, 0, stream>>>(dstI, cnt, E);
    pairsum_k<<<NBK, 256, 0, stream>>>(cnt, btot, N);
    bscan_k<<<1, 512, 0, stream>>>(btot, bboff, NBK);
    cursorpad_k<<<NBK, 256, 0, stream>>>(cnt, bboff, cursor, dinv, qcur, csr_src, N);
    scatter_k<<<1563, 256, 0, stream>>>(srcI, dstI, cursor, qcur, csr_src, E);

    const int gGemm = (N + 63) / 64;
    const int gAgg = (N + 7) / 8;            // 4 pairs (8 nodes) per block

    // ---- layer 1 ----
    gemm_mfma<true><<<gGemm, 256, 0, stream>>>(x, Wbf1, dinv, gbuf, N);
    agg_csr<<<gAgg, 256, 0, stream>>>(cursor, cnt, csr_src, gbuf, dinv, b1,
                                      bufA, N);

    // ---- layer 2 ----
    gemm_mfma<false><<<gGemm, 256, 0, stream>>>(bufA, Wbf2, dinv, gbuf, N);
    agg_csr<<<gAgg, 256, 0, stream>>>(cursor, cnt, csr_src, gbuf, dinv, b2,
                                      bufA, N);

    // ---- pool + classifier ----
    pool_kernel<<<PBLK, 256, 0, stream>>>(bufA, partial, N);
    final_kernel<<<1, 128, 0, stream>>>(partial, Wc, bc, (float*)d_out, N, C);
}

// Round 13
// 265.767 us; speedup vs baseline: 1.5509x; 1.5509x over previous
//
#include <hip/hip_runtime.h>
#include <hip/hip_bf16.h>

// GCN: h1 = relu(Agg(x@W1)+b1); h2 = relu(Agg(h1@W2)+b2); out = mean(h2)@Wc + bc
// Agg via CSR gather; g = (X@W)*dinv stored OCP fp8 e4m3 (128B node-major rows,
// plus ONE ZERO ROW at index N for CSR padding).
// == r13: EXACT REVERT to r10 (measured 267.4us, the session optimum). ==
// Bracketing evidence (do not re-try):
//  - r11 quad agg (4 edges/instr): 283us. VGPR 50->80 cut occupancy 8->6
//    waves/SIMD; slot inflation E[ceil(max4/16)]=2.0 vs pair 1.7.
//  - r12 single-pass scatter build: 412us. scatter_k=130us: 1.6M random 4B
//    csr writes -> 64x write amplification (WRITE=105MB) + value-returning
//    atomicAdd dependent chain. Two-pass LDS-staged build is 2.6x faster.
//  - r1-r3 plane-sharded L2-resident gather: strictly worse (2x L2
//    transactions/byte). Node-major 128B rows win.
// r10: PAIR agg: wave = 2 nodes (lanes 0-31 A, 32-63 B, 4 feats/lane), gather
// = 256B = 2 rows = 2 EDGES PER VMEM INSTR; pair-padded round-interleaved CSR
// (16A|16B per round); pad -> zero row. r9: padded CSR kills tail masking.
// [r8 inline-asm s_load aborted on HW - plain HIP only.]
// r7: masked tail. r6: pool atomic-serialization fix (62->6us). r5: 32-bit
// byte-offset addressing. r4: fp8 activations (agg not store-bound).
// NOTE: harness re-poisons 256MB workspace per iteration (~40us fill visible
// in rocprof) - untouchable; controllable budget ~= dur - 40us.
// CSR build atomic-free; ALL build kernels >= 391 blocks.
// GEMMs: mfma_f32_16x16x32_bf16, LDS-free, W pre-packed to k-block layout.

#define FEAT 128
#define CHUNK 4096      // edges per chunk (391 chunks)
#define MAXBUCK 512     // max node-buckets (N <= 131072); also NC cap
#define ECAP 12288      // LDS edge staging cap in bucket_scat (48 KB of int)
#define PBLK 512        // pool stage-1 blocks
#define BPAD 16384      // per-bucket padded-layout slack (pair padding, safe to deg<=72)

typedef __attribute__((ext_vector_type(8))) short short8;
typedef __attribute__((ext_vector_type(4))) float float4v;
typedef __attribute__((ext_vector_type(2))) float floatx2;

union I4S8 { int4 i; short8 s; };

static __device__ inline unsigned short f2bf(float f) {
    union { __hip_bfloat16 h; unsigned short u; } cv;
    cv.h = __float2bfloat16(f);
    return cv.u;
}

// ---- OCP fp8 e4m3 helpers ----
static __device__ inline floatx2 fp8x2_dec(unsigned int u) {
#if __has_builtin(__builtin_amdgcn_cvt_pk_f32_fp8)
    return __builtin_amdgcn_cvt_pk_f32_fp8((int)u, false);
#else
    floatx2 r;
    unsigned int b0 = u & 0xFFu, b1 = (u >> 8) & 0xFFu;
    r.x = __uint_as_float(((b0 & 0x80u) << 24) | ((b0 & 0x7Fu) << 20)) * 0x1p+120f;
    r.y = __uint_as_float(((b1 & 0x80u) << 24) | ((b1 & 0x7Fu) << 20)) * 0x1p+120f;
    return r;
#endif
}

static __device__ inline floatx2 fp8x2_dec_hi(unsigned int u) {
#if __has_builtin(__builtin_amdgcn_cvt_pk_f32_fp8)
    return __builtin_amdgcn_cvt_pk_f32_fp8((int)u, true);
#else
    return fp8x2_dec(u >> 16);
#endif
}

// pack two floats -> two fp8 e4m3 bytes (low word)
static __device__ inline unsigned short fp8x2_enc(float x, float y) {
#if __has_builtin(__builtin_amdgcn_cvt_pk_fp8_f32)
    return (unsigned short)(__builtin_amdgcn_cvt_pk_fp8_f32(x, y, 0, false) & 0xFFFF);
#else
    auto enc1 = [](float f) -> unsigned int {
        unsigned int u = __float_as_uint(f);
        unsigned int s = (u >> 24) & 0x80u;
        float a = fabsf(f);
        a = fminf(a, 448.0f);
        unsigned int code;
        if (a < 0.015625f) {
            code = (unsigned int)(int)rintf(a * 512.0f);
        } else {
            unsigned int au = __float_as_uint(a);
            unsigned int r = au + 0x0007FFFFu + ((au >> 20) & 1u);
            unsigned int e = (r >> 23) - 120u;
            unsigned int m = (r >> 20) & 7u;
            code = (e << 3) | m;
            if (code > 0x7Eu) code = 0x7Eu;
        }
        return code | s;
    };
    return (unsigned short)(enc1(x) | (enc1(y) << 8));
#endif
}

static __device__ inline unsigned char fp8enc(float f) {
#if __has_builtin(__builtin_amdgcn_cvt_pk_fp8_f32)
    return (unsigned char)(__builtin_amdgcn_cvt_pk_fp8_f32(f, 0.0f, 0, false) & 0xFF);
#else
    return (unsigned char)(fp8x2_enc(f, 0.0f) & 0xFF);
#endif
}

// ---- build phase 1: per-chunk histogram over node buckets (dst>>8) ----
__global__ __launch_bounds__(256) void hist2(const int* __restrict__ dst,
                                             int* __restrict__ hist,
                                             int nE, int NC, int nbuck) {
    __shared__ int h[MAXBUCK];
    int c = blockIdx.x, t = threadIdx.x;
    for (int i = t; i < nbuck; i += 256) h[i] = 0;
    __syncthreads();
    int beg = c * CHUNK, end = min(nE, beg + CHUNK);
    for (int e = beg + t; e < end; e += 256)
        atomicAdd(&h[dst[e] >> 8], 1);
    __syncthreads();
    for (int i = t; i < nbuck; i += 256) hist[i * NC + c] = h[i];
}

// ---- phase 2a: per-bucket totals (wide: one block per bucket) ----
__global__ __launch_bounds__(256) void rowsum_k(const int* __restrict__ hist,
                                                int* __restrict__ btot, int NC) {
    __shared__ int red[256];
    int b = blockIdx.x, t = threadIdx.x;
    int s = 0;
    for (int c = t; c < NC; c += 256) s += hist[b * NC + c];
    red[t] = s;
    __syncthreads();
    for (int o = 128; o > 0; o >>= 1) {
        if (t < o) red[t] += red[t + o];
        __syncthreads();
    }
    if (t == 0) btot[b] = red[0];
}

// ---- phase 2b: exclusive scan of bucket totals (nbuck <= 512) ----
__global__ __launch_bounds__(512) void bscan_k(const int* __restrict__ btot,
                                               int* __restrict__ bboff, int nbuck) {
    __shared__ int sc[512];
    int t = threadIdx.x;
    int v = (t < nbuck) ? btot[t] : 0;
    sc[t] = v;
    __syncthreads();
    for (int o = 1; o < 512; o <<= 1) {
        int add = (t >= o) ? sc[t - o] : 0;
        __syncthreads();
        sc[t] += add;
        __syncthreads();
    }
    if (t < nbuck) {
        bboff[t] = sc[t] - v;
        if (t == nbuck - 1) bboff[nbuck] = sc[t];
    }
}

// ---- phase 2c: per-(bucket,chunk) offsets (wide: block-parallel scan, NC<=512) ----
__global__ __launch_bounds__(512) void rowoff_k(const int* __restrict__ hist,
                                                const int* __restrict__ bboff,
                                                int* __restrict__ hoff, int NC) {
    __shared__ int sc[512];
    int b = blockIdx.x, t = threadIdx.x;
    int v = (t < NC) ? hist[b * NC + t] : 0;
    sc[t] = v;
    __syncthreads();
    for (int o = 1; o < 512; o <<= 1) {
        int add = (t >= o) ? sc[t - o] : 0;
        __syncthreads();
        sc[t] += add;
        __syncthreads();
    }
    if (t < NC) hoff[b * NC + t] = bboff[b] + sc[t] - v;
}

// ---- phase 3: pack (src<<8|dloc) bucket-grouped; LDS cursors ----
__global__ __launch_bounds__(256) void fill2(const int* __restrict__ src,
                                             const int* __restrict__ dst,
                                             const int* __restrict__ off,
                                             int* __restrict__ binned,
                                             int nE, int NC, int nbuck) {
    __shared__ int cur[MAXBUCK];
    int c = blockIdx.x, t = threadIdx.x;
    for (int i = t; i < nbuck; i += 256) cur[i] = off[i * NC + c];
    __syncthreads();
    int beg = c * CHUNK, end = min(nE, beg + CHUNK);
    for (int e = beg + t; e < end; e += 256) {
        int d = dst[e];
        int pos = atomicAdd(&cur[d >> 8], 1);
        binned[pos] = (src[e] << 8) | (d & 255);
    }
}

// ---- phase 4: per-bucket count + dinv + cursor + PAIR-PADDED csr scatter ----
// Pair p = nodes (2p, 2p+1). pairLen = ceil(max(dA,dB)/16)*16; pair region =
// 2*pairLen slots, round-interleaved: round r = [A slots 16r..] then [B slots].
// Node (p,h) slot q -> poff[p] + (q>>4)*32 + h*16 + (q&15). Pad -> zero row.
// cnt[node] = pairLen (agg loop bound); csr entries PRE-SHIFTED (src<<7).
__global__ __launch_bounds__(256) void bucket_scat(const int* __restrict__ binned,
                                                   const int* __restrict__ bboff,
                                                   int* __restrict__ cnt,
                                                   float* __restrict__ dinv,
                                                   int* __restrict__ cursor,
                                                   int* __restrict__ csr_src, int n) {
    __shared__ int se[ECAP];
    __shared__ int lcnt[256];
    __shared__ int lcur[256];
    __shared__ int ssc[256];
    __shared__ int poff[128];
    int b = blockIdx.x, t = threadIdx.x;
    int node0 = b << 8;
    int nloc = min(256, n - node0);
    int ebeg = bboff[b], eend = bboff[b + 1];
    int ne = eend - ebeg;
    int pbase = (ebeg + b * BPAD + 15) & ~15;   // 16-aligned padded bucket base
    int zOff = n << 7;                          // zero-row byte offset
    lcnt[t] = 0;
    lcur[t] = 0;
    __syncthreads();
    bool staged = (ne <= ECAP);
    if (staged) {
        for (int i = t; i < ne; i += 256) {
            int e = binned[ebeg + i];
            se[i] = e;
            atomicAdd(&lcnt[e & 255], 1);
        }
    } else {
        for (int i = t; i < ne; i += 256)
            atomicAdd(&lcnt[binned[ebeg + i] & 255], 1);
    }
    __syncthreads();
    int myc = (t < nloc) ? lcnt[t] : 0;
    // pair slot totals (thread t<128 owns pair t)
    int npair = (nloc + 1) >> 1;
    int pairSlots = 0;
    if (t < npair) {
        int mx = max(lcnt[2 * t], lcnt[2 * t + 1]);
        pairSlots = 2 * ((mx + 15) & ~15);
    }
    ssc[t] = pairSlots;
    __syncthreads();
    for (int o = 1; o < 256; o <<= 1) {
        int add = (t >= o) ? ssc[t - o] : 0;
        __syncthreads();
        ssc[t] += add;
        __syncthreads();
    }
    if (t < npair) poff[t] = ssc[t] - pairSlots;   // exclusive pair offset
    __syncthreads();
    if (t < nloc) {
        int p = t >> 1;
        int pl = ((max(lcnt[p * 2], lcnt[p * 2 + 1]) + 15) & ~15);
        cnt[node0 + t] = pl;                       // pairLen (rounds*16)
        dinv[node0 + t] = rsqrtf((float)(myc + 1));
        cursor[node0 + t] = pbase + poff[p];       // pair base (slot units)
    }
    __syncthreads();
    if (staged) {
        for (int i = t; i < ne; i += 256) {
            int e = se[i];
            int loc = e & 255;
            int q = atomicAdd(&lcur[loc], 1);
            int slot = pbase + poff[loc >> 1] + ((q >> 4) << 5) + ((loc & 1) << 4) + (q & 15);
            csr_src[slot] = (int)(((unsigned int)e >> 8) << 7);
        }
    } else {
        for (int i = t; i < ne; i += 256) {
            int e = binned[ebeg + i];
            int loc = e & 255;
            int q = atomicAdd(&lcur[loc], 1);
            int slot = pbase + poff[loc >> 1] + ((q >> 4) << 5) + ((loc & 1) << 4) + (q & 15);
            csr_src[slot] = (int)(((unsigned int)e >> 8) << 7);
        }
    }
    // pad fill (covers missing partner of an odd last node too)
    int nlocp = (nloc + 1) & ~1;
    if (t < nlocp) {
        int p = t >> 1, h = t & 1;
        int pl = ((max(lcnt[p * 2], lcnt[p * 2 + 1]) + 15) & ~15);
        int base = pbase + poff[p] + (h << 4);
        for (int q = myc; q < pl; q++)
            csr_src[base + ((q >> 4) << 5) + (q & 15)] = zOff;
    }
}

// ---- W pre-pack (both layers) + gbuf zero-row init ----
__global__ __launch_bounds__(256) void wprep2(const float* __restrict__ W1,
                                              const float* __restrict__ W2,
                                              unsigned short* __restrict__ Wbf1,
                                              unsigned short* __restrict__ Wbf2,
                                              unsigned char* __restrict__ gbuf,
                                              int n) {
    int tid = blockIdx.x * 256 + threadIdx.x;   // 32768 threads
    if (tid < 32)
        ((unsigned int*)(gbuf + (size_t)n * FEAT))[tid] = 0u;  // zero row N
    const float* W = (tid < 16384) ? W1 : W2;
    unsigned short* O = (tid < 16384) ? Wbf1 : Wbf2;
    int id = tid & 16383;
    int chunk = id >> 3, j = id & 7;
    int kb = chunk >> 7, nn = chunk & 127;
    O[id] = f2bf(W[(kb * 8 + j) * FEAT + nn]);
}

// ---- MFMA GEMM: gout[N][128](fp8) = bf16(X) @ Wbf * dinv[row] ----
// AFP32=true: X is fp32 rows. AFP32=false: X is fp8 e4m3 rows (exact->bf16).
template <bool AFP32>
__global__ __launch_bounds__(256) void gemm_mfma(const void* __restrict__ Xv,
                                                 const unsigned short* __restrict__ Wbf,
                                                 const float* __restrict__ dinv,
                                                 unsigned char* __restrict__ gout,
                                                 int n) {
    int wave = threadIdx.x >> 6, lane = threadIdx.x & 63;
    int m0 = blockIdx.x * 64 + wave * 16;
    if (m0 >= n) return;
    int col = lane & 15, quad = lane >> 4;
    int mc = min(m0 + col, n - 1);

    short8 afr[4];
    if (AFP32) {
        const float* X = (const float*)Xv;
        const float* xr = X + (size_t)mc * FEAT + quad * 8;
#pragma unroll
        for (int ks = 0; ks < 4; ks++) {
            float4 lo = *(const float4*)(xr + ks * 32);
            float4 hi = *(const float4*)(xr + ks * 32 + 4);
            short8 a;
            a[0] = (short)f2bf(lo.x); a[1] = (short)f2bf(lo.y);
            a[2] = (short)f2bf(lo.z); a[3] = (short)f2bf(lo.w);
            a[4] = (short)f2bf(hi.x); a[5] = (short)f2bf(hi.y);
            a[6] = (short)f2bf(hi.z); a[7] = (short)f2bf(hi.w);
            afr[ks] = a;
        }
    } else {
        const unsigned char* X8 = (const unsigned char*)Xv;
        const unsigned char* xr = X8 + (size_t)mc * FEAT + quad * 8;
#pragma unroll
        for (int ks = 0; ks < 4; ks++) {
            uint2 u2 = *(const uint2*)(xr + ks * 32);
            floatx2 p0 = fp8x2_dec(u2.x);
            floatx2 p1 = fp8x2_dec_hi(u2.x);
            floatx2 p2 = fp8x2_dec(u2.y);
            floatx2 p3 = fp8x2_dec_hi(u2.y);
            short8 a;
            a[0] = (short)f2bf(p0.x); a[1] = (short)f2bf(p0.y);
            a[2] = (short)f2bf(p1.x); a[3] = (short)f2bf(p1.y);
            a[4] = (short)f2bf(p2.x); a[5] = (short)f2bf(p2.y);
            a[6] = (short)f2bf(p3.x); a[7] = (short)f2bf(p3.y);
            afr[ks] = a;
        }
    }

    float dvr[4];
#pragma unroll
    for (int r = 0; r < 4; r++)
        dvr[r] = dinv[min(m0 + quad * 4 + r, n - 1)];

    const int4* Wb = (const int4*)Wbf;
#pragma unroll
    for (int nt = 0; nt < 8; nt++) {
        float4v acc = {0.f, 0.f, 0.f, 0.f};
#pragma unroll
        for (int ks = 0; ks < 4; ks++) {
            int kb = ks * 4 + quad;
            I4S8 u; u.i = Wb[kb * FEAT + nt * 16 + col];
            acc = __builtin_amdgcn_mfma_f32_16x16x32_bf16(afr[ks], u.s, acc, 0, 0, 0);
        }
#pragma unroll
        for (int r = 0; r < 4; r++) {
            int row = m0 + quad * 4 + r;
            if (row < n)
                gout[(size_t)row * FEAT + nt * 16 + col] = fp8enc(acc[r] * dvr[r]);
        }
    }
}

// ---- agg: PAIRED CSR gather + bias + relu -> fp8 rows (2 nodes per wave) ----
// lanes 0-31 = node A, 32-63 = node B; each lane owns 4 feats (1 dword).
// Gather instr = dword x64 = 2 rows = 2 edges. Idx: each half loads its own
// 16-idx block (4 int4 at pairBase + r*128 + half*64). Rounds = pairLen/16.
__global__ __launch_bounds__(256) void agg_csr(const int* __restrict__ cursor,
                                               const int* __restrict__ cnt,
                                               const int* __restrict__ csr_src,
                                               const unsigned char* __restrict__ gbuf,
                                               const float* __restrict__ dinv,
                                               const float* __restrict__ bias,
                                               unsigned char* __restrict__ outb,
                                               int n) {
    int pair = blockIdx.x * 4 + (threadIdx.x >> 6);
    int nodeA = pair << 1;
    if (nodeA >= n) return;
    unsigned lane = threadIdx.x & 63;
    unsigned half = lane >> 5;                  // 0 = A, 1 = B
    unsigned sub = lane & 31;
    int node = nodeA + (int)half;               // n even -> node < n
    unsigned fb = sub << 2;                     // 4B feature offset in row

    int curS = __builtin_amdgcn_readfirstlane(cursor[nodeA]);  // pair base (slots)
    int plS = __builtin_amdgcn_readfirstlane(cnt[nodeA]);      // pairLen
    const unsigned char* csrB = (const unsigned char*)csr_src;
    const unsigned char* ip0 = csrB + (((size_t)(unsigned)curS) << 2) + (half << 6);

    unsigned su = *(const unsigned*)(gbuf + ((((unsigned)node) << 7) | fb));
    floatx2 a01 = fp8x2_dec(su), a23 = fp8x2_dec_hi(su);       // self-loop
    floatx2 b01 = {0.f, 0.f}, b23 = {0.f, 0.f};

    int rounds = plS >> 4;
    for (int r = 0; r < rounds; r++) {
        const unsigned char* p = ip0 + ((size_t)(unsigned)r << 7);
        int4 w0 = *(const int4*)(p);
        int4 w1 = *(const int4*)(p + 16);
        int4 w2 = *(const int4*)(p + 32);
        int4 w3 = *(const int4*)(p + 48);
        unsigned uu[16];
        uu[0]  = *(const unsigned*)(gbuf + ((unsigned)w0.x | fb));
        uu[1]  = *(const unsigned*)(gbuf + ((unsigned)w0.y | fb));
        uu[2]  = *(const unsigned*)(gbuf + ((unsigned)w0.z | fb));
        uu[3]  = *(const unsigned*)(gbuf + ((unsigned)w0.w | fb));
        uu[4]  = *(const unsigned*)(gbuf + ((unsigned)w1.x | fb));
        uu[5]  = *(const unsigned*)(gbuf + ((unsigned)w1.y | fb));
        uu[6]  = *(const unsigned*)(gbuf + ((unsigned)w1.z | fb));
        uu[7]  = *(const unsigned*)(gbuf + ((unsigned)w1.w | fb));
        uu[8]  = *(const unsigned*)(gbuf + ((unsigned)w2.x | fb));
        uu[9]  = *(const unsigned*)(gbuf + ((unsigned)w2.y | fb));
        uu[10] = *(const unsigned*)(gbuf + ((unsigned)w2.z | fb));
        uu[11] = *(const unsigned*)(gbuf + ((unsigned)w2.w | fb));
        uu[12] = *(const unsigned*)(gbuf + ((unsigned)w3.x | fb));
        uu[13] = *(const unsigned*)(gbuf + ((unsigned)w3.y | fb));
        uu[14] = *(const unsigned*)(gbuf + ((unsigned)w3.z | fb));
        uu[15] = *(const unsigned*)(gbuf + ((unsigned)w3.w | fb));
#pragma unroll
        for (int k = 0; k < 16; k += 2) {
            a01 += fp8x2_dec(uu[k]);
            a23 += fp8x2_dec_hi(uu[k]);
            b01 += fp8x2_dec(uu[k + 1]);
            b23 += fp8x2_dec_hi(uu[k + 1]);
        }
    }
    a01 += b01;
    a23 += b23;
    float dv = dinv[node];
    float4 bv = ((const float4*)bias)[sub];
    float r0 = fmaxf(a01.x * dv + bv.x, 0.0f);
    float r1 = fmaxf(a01.y * dv + bv.y, 0.0f);
    float r2 = fmaxf(a23.x * dv + bv.z, 0.0f);
    float r3 = fmaxf(a23.y * dv + bv.w, 0.0f);
    unsigned outw = (unsigned)fp8x2_enc(r0, r1) | ((unsigned)fp8x2_enc(r2, r3) << 16);
    *(unsigned*)(outb + ((((unsigned)node) << 7) | fb)) = outw;
}

// ---- mean pool stage 1: per-block partial sums, NO global atomics ----
__global__ __launch_bounds__(256) void pool_kernel(const unsigned char* __restrict__ a,
                                                   float* __restrict__ partial, int n) {
    __shared__ float red[16][132];   // +4 pad
    int t = threadIdx.x, b = blockIdx.x;
    int fg = t & 15;
    int rg = t >> 4;
    unsigned fb = (unsigned)fg << 3;             // feature byte offset
    floatx2 s01 = {0.f, 0.f}, s23 = {0.f, 0.f}, s45 = {0.f, 0.f}, s67 = {0.f, 0.f};
    for (int i = (b << 4) | rg; i < n; i += PBLK * 16) {
        uint2 u2 = *(const uint2*)(a + (((unsigned)i << 7) | fb));
        s01 += fp8x2_dec(u2.x);
        s23 += fp8x2_dec_hi(u2.x);
        s45 += fp8x2_dec(u2.y);
        s67 += fp8x2_dec_hi(u2.y);
    }
    red[rg][fb + 0] = s01.x; red[rg][fb + 1] = s01.y;
    red[rg][fb + 2] = s23.x; red[rg][fb + 3] = s23.y;
    red[rg][fb + 4] = s45.x; red[rg][fb + 5] = s45.y;
    red[rg][fb + 6] = s67.x; red[rg][fb + 7] = s67.y;
    __syncthreads();
    if (t < FEAT) {
        float s = 0.0f;
#pragma unroll
        for (int k = 0; k < 16; k++) s += red[k][t];
        partial[b * FEAT + t] = s;
    }
}

// ---- final: reduce partials; out[c] = (pooled/N) . Wc[:,c] + bc[c] ----
__global__ __launch_bounds__(128) void final_kernel(const float* __restrict__ partial,
                                                    const float* __restrict__ Wc,
                                                    const float* __restrict__ bc,
                                                    float* __restrict__ out,
                                                    int n, int C) {
    __shared__ float p[FEAT];
    int t = threadIdx.x;
    float s = 0.0f;
    for (int b = 0; b < PBLK; b++) s += partial[b * FEAT + t];
    p[t] = s * (1.0f / (float)n);
    __syncthreads();
    if (t < C) {
        float acc = bc[t];
        for (int h = 0; h < FEAT; h++)
            acc += p[h] * Wc[h * C + t];
        out[t] = acc;
    }
}

extern "C" void kernel_launch(void* const* d_in, const int* in_sizes, int n_in,
                              void* d_out, int out_size, void* d_ws, size_t ws_size,
                              hipStream_t stream) {
    const float* x  = (const float*)d_in[0];
    const int*   ei = (const int*)d_in[1];
    const float* W1 = (const float*)d_in[2];
    const float* b1 = (const float*)d_in[3];
    const float* W2 = (const float*)d_in[4];
    const float* b2 = (const float*)d_in[5];
    const float* Wc = (const float*)d_in[6];
    const float* bc = (const float*)d_in[7];

    const int N = in_sizes[0] / FEAT;        // 100000
    const int E = in_sizes[1] / 2;           // 1600000
    const int C = out_size;                  // 32
    const int* srcI = ei;
    const int* dstI = ei + E;
    const int NC = (E + CHUNK - 1) / CHUNK;  // edge chunks (391, <= 512)
    const int NBK = (N + 255) >> 8;          // node buckets (391, <= MAXBUCK)
    const size_t csrCap = (size_t)E + (size_t)NBK * BPAD + 64;  // padded layout

    // workspace carve (256B aligned)
    auto align256 = [](size_t v) { return (v + 255) & ~(size_t)255; };
    char* w = (char*)d_ws;
    int*            cnt     = (int*)w;            w += align256((size_t)N * 4);
    float*          dinv    = (float*)w;          w += align256((size_t)N * 4);
    int*            cursor  = (int*)w;            w += align256((size_t)N * 4);
    int*            csr_src = (int*)w;            w += align256(csrCap * 4);
    int*            binned  = (int*)w;            w += align256((size_t)E * 4);
    int*            hist    = (int*)w;            w += align256((size_t)NBK * NC * 4);
    int*            hoff    = (int*)w;            w += align256((size_t)NBK * NC * 4);
    int*            btot    = (int*)w;            w += align256((size_t)NBK * 4);
    int*            bboff   = (int*)w;            w += align256((size_t)(NBK + 1) * 4);
    unsigned short* Wbf1    = (unsigned short*)w; w += align256((size_t)FEAT * FEAT * 2);
    unsigned short* Wbf2    = (unsigned short*)w; w += align256((size_t)FEAT * FEAT * 2);
    unsigned char*  gbuf    = (unsigned char*)w;  w += align256((size_t)(N + 1) * FEAT);
    unsigned char*  bufA    = (unsigned char*)w;  w += align256((size_t)N * FEAT);
    float*          partial = (float*)w;          w += align256((size_t)PBLK * FEAT * 4);

    // W pre-pack (both layers) + gbuf zero-row init
    wprep2<<<128, 256, 0, stream>>>(W1, W2, Wbf1, Wbf2, gbuf, N);

    // ---- atomic-free CSR build (all kernels >= 391 blocks except bscan) ----
    hist2<<<NC, 256, 0, stream>>>(dstI, hist, E, NC, NBK);
    rowsum_k<<<NBK, 256, 0, stream>>>(hist, btot, NC);
    bscan_k<<<1, 512, 0, stream>>>(btot, bboff, NBK);
    rowoff_k<<<NBK, 512, 0, stream>>>(hist, bboff, hoff, NC);
    fill2<<<NC, 256, 0, stream>>>(srcI, dstI, hoff, binned, E, NC, NBK);
    bucket_scat<<<NBK, 256, 0, stream>>>(binned, bboff, cnt, dinv, cursor, csr_src, N);

    const int gGemm = (N + 63) / 64;
    const int gAgg = (N + 7) / 8;            // 4 pairs (8 nodes) per block

    // ---- layer 1 ----
    gemm_mfma<true><<<gGemm, 256, 0, stream>>>(x, Wbf1, dinv, gbuf, N);
    agg_csr<<<gAgg, 256, 0, stream>>>(cursor, cnt, csr_src, gbuf, dinv, b1,
                                      bufA, N);

    // ---- layer 2 ----
    gemm_mfma<false><<<gGemm, 256, 0, stream>>>(bufA, Wbf2, dinv, gbuf, N);
    agg_csr<<<gAgg, 256, 0, stream>>>(cursor, cnt, csr_src, gbuf, dinv, b2,
                                      bufA, N);

    // ---- pool + classifier ----
    pool_kernel<<<PBLK, 256, 0, stream>>>(bufA, partial, N);
    final_kernel<<<1, 128, 0, stream>>>(partial, Wc, bc, (float*)d_out, N, C);
}